// Round 8
// baseline (165.595 us; speedup 1.0000x reference)
//
#include <hip/hip_runtime.h>

#define NALL 1024
#define NH   512
#define NCOL 8
#define ROWS_PER_BLOCK 64
#define THREADS 256
#define CHUNKS 16
#define SAMPLES 2
#define PRE 8                         // rows prefetched before the prologue

typedef float f32x4 __attribute__((ext_vector_type(4)));

__device__ __forceinline__ f32x4 nt_load(const float* p) {
    return __builtin_nontemporal_load(reinterpret_cast<const f32x4*>(p));
}

// Fused, fully barrier-free kernel. Block = (sample pair, 64-row chunk),
// 4 waves. Per wave: vectorized redundant column-norm reduce (u,v are 32 KB,
// L2-resident; shfl butterfly), private wl copy in LDS (lane i writes row i,
// wave reads only its own copy -> no __syncthreads anywhere), right fragment
// in regs. First 8 x-rows are issued BEFORE the prologue so cold HBM latency
// covers the norm computation. Main loop = compiler-scheduled unroll 8
// (R6 structure, the best measured).
// out[b][q*8+c], q = ih + 2*jh:
//   q0 = uJu (i<512, j<512),  q1 = vJu (i>=512, j<512),
//   q2 = uJv (i<512, j>=512), q3 = vJv (i>=512, j>=512)
__global__ __launch_bounds__(THREADS) void jxy_kernel(
    const float* __restrict__ x, const float* __restrict__ u,
    const float* __restrict__ v, float* __restrict__ out) {
    const int bid   = blockIdx.x;
    const int pair  = bid >> 4;
    const int chunk = bid & (CHUNKS - 1);
    const int r0    = chunk * ROWS_PER_BLOCK;
    const int ih    = (r0 >= NH) ? 1 : 0;   // 64-row chunks never straddle halves
    const int rloc  = r0 - ih * NH;

    const int tid  = threadIdx.x;
    const int wave = tid >> 6;
    const int lane = tid & 63;
    const int jbase = wave * 256 + lane * 4;   // this lane's 4 fixed j positions
    const int jh    = (jbase >= NH) ? 1 : 0;   // uniform per wave
    const int jloc  = jbase - jh * NH;

    const float* xrow0 = x + ((size_t)(pair * SAMPLES) * NALL + r0) * NALL + jbase;
    const float* xrow1 = xrow0 + (size_t)NALL * NALL;

    // ---- prefetch rows 0..7 of sample 0 (HBM latency covers the prologue) ----
    f32x4 pre[PRE];
#pragma unroll
    for (int k = 0; k < PRE; ++k)
        pre[k] = nt_load(xrow0 + (size_t)k * NALL);

    // ---- barrier-free prologue: per-wave joint column norms (vectorized) ----
    float nrm[NCOL];
#pragma unroll
    for (int c = 0; c < NCOL; ++c) nrm[c] = 0.f;
    for (int r = lane; r < NH; r += 64) {
        const f32x4* up = reinterpret_cast<const f32x4*>(u + r * NCOL);
        const f32x4* vp = reinterpret_cast<const f32x4*>(v + r * NCOL);
        f32x4 a0 = up[0], a1 = up[1], b0 = vp[0], b1 = vp[1];
        nrm[0] = fmaf(a0.x, a0.x, fmaf(b0.x, b0.x, nrm[0]));
        nrm[1] = fmaf(a0.y, a0.y, fmaf(b0.y, b0.y, nrm[1]));
        nrm[2] = fmaf(a0.z, a0.z, fmaf(b0.z, b0.z, nrm[2]));
        nrm[3] = fmaf(a0.w, a0.w, fmaf(b0.w, b0.w, nrm[3]));
        nrm[4] = fmaf(a1.x, a1.x, fmaf(b1.x, b1.x, nrm[4]));
        nrm[5] = fmaf(a1.y, a1.y, fmaf(b1.y, b1.y, nrm[5]));
        nrm[6] = fmaf(a1.z, a1.z, fmaf(b1.z, b1.z, nrm[6]));
        nrm[7] = fmaf(a1.w, a1.w, fmaf(b1.w, b1.w, nrm[7]));
    }
#pragma unroll
    for (int c = 0; c < NCOL; ++c) {
#pragma unroll
        for (int off = 32; off >= 1; off >>= 1)
            nrm[c] += __shfl_xor(nrm[c], off, 64);
    }
    float inv[NCOL];
#pragma unroll
    for (int c = 0; c < NCOL; ++c) inv[c] = 1.0f / sqrtf(nrm[c]);

    // ---- per-wave private wl copy: lane i writes row i (no barrier needed;
    //      within-wave ds_write->ds_read ordering is enforced by lgkmcnt) ----
    __shared__ __align__(16) float wl[4][ROWS_PER_BLOCK * NCOL];
    {
        const float* rawl = ih ? v : u;
        const f32x4* rp = reinterpret_cast<const f32x4*>(rawl + (size_t)(rloc + lane) * NCOL);
        f32x4 l0 = rp[0], l1 = rp[1];
        l0.x *= inv[0]; l0.y *= inv[1]; l0.z *= inv[2]; l0.w *= inv[3];
        l1.x *= inv[4]; l1.y *= inv[5]; l1.z *= inv[6]; l1.w *= inv[7];
        f32x4* wp = reinterpret_cast<f32x4*>(&wl[wave][lane * NCOL]);
        wp[0] = l0; wp[1] = l1;
    }
    const float* wlw = &wl[wave][0];

    // ---- right fragment in registers ----
    const float* rawr = jh ? v : u;
    float wr[4][NCOL];
#pragma unroll
    for (int k = 0; k < 4; ++k) {
        const f32x4* p = reinterpret_cast<const f32x4*>(rawr + (size_t)(jloc + k) * NCOL);
        f32x4 a = p[0], bq = p[1];
        wr[k][0] = a.x * inv[0];  wr[k][1] = a.y * inv[1];
        wr[k][2] = a.z * inv[2];  wr[k][3] = a.w * inv[3];
        wr[k][4] = bq.x * inv[4]; wr[k][5] = bq.y * inv[5];
        wr[k][6] = bq.z * inv[6]; wr[k][7] = bq.w * inv[7];
    }

#define COMPUTE(xv, row)                                                      \
    {                                                                         \
        float t[NCOL];                                                        \
        _Pragma("unroll")                                                     \
        for (int c = 0; c < NCOL; ++c)                                        \
            t[c] = fmaf((xv).x, wr[0][c],                                     \
                   fmaf((xv).y, wr[1][c],                                     \
                   fmaf((xv).z, wr[2][c],                                     \
                        (xv).w * wr[3][c])));                                 \
        f32x4 wa = *reinterpret_cast<const f32x4*>(&wlw[(row) * NCOL]);       \
        f32x4 wb = *reinterpret_cast<const f32x4*>(&wlw[(row) * NCOL + 4]);   \
        acc[0] = fmaf(wa.x, t[0], acc[0]);                                    \
        acc[1] = fmaf(wa.y, t[1], acc[1]);                                    \
        acc[2] = fmaf(wa.z, t[2], acc[2]);                                    \
        acc[3] = fmaf(wa.w, t[3], acc[3]);                                    \
        acc[4] = fmaf(wb.x, t[4], acc[4]);                                    \
        acc[5] = fmaf(wb.y, t[5], acc[5]);                                    \
        acc[6] = fmaf(wb.z, t[6], acc[6]);                                    \
        acc[7] = fmaf(wb.w, t[7], acc[7]);                                    \
    }

    float acc[NCOL];
#pragma unroll
    for (int c = 0; c < NCOL; ++c) acc[c] = 0.f;

    // ---- sample 0: consume prefetch, then stream rows 8..63 (unroll 8) ----
#pragma unroll
    for (int k = 0; k < PRE; ++k)
        COMPUTE(pre[k], k);

#pragma unroll 8
    for (int r = PRE; r < ROWS_PER_BLOCK; ++r) {
        f32x4 xv = nt_load(xrow0 + (size_t)r * NALL);
        COMPUTE(xv, r);
    }

#pragma unroll
    for (int c = 0; c < NCOL; ++c) {
#pragma unroll
        for (int off = 32; off >= 1; off >>= 1)
            acc[c] += __shfl_xor(acc[c], off, 64);
    }
    const int q = ih + 2 * jh;
    if (lane == 0) {
        float* o = out + (size_t)(pair * SAMPLES) * (4 * NCOL) + q * NCOL;
#pragma unroll
        for (int c = 0; c < NCOL; ++c)
            atomicAdd(o + c, acc[c]);
    }

    // ---- sample 1: stream rows 0..63 (unroll 8) ----
#pragma unroll
    for (int c = 0; c < NCOL; ++c) acc[c] = 0.f;

#pragma unroll 8
    for (int r = 0; r < ROWS_PER_BLOCK; ++r) {
        f32x4 xv = nt_load(xrow1 + (size_t)r * NALL);
        COMPUTE(xv, r);
    }

#pragma unroll
    for (int c = 0; c < NCOL; ++c) {
#pragma unroll
        for (int off = 32; off >= 1; off >>= 1)
            acc[c] += __shfl_xor(acc[c], off, 64);
    }
    if (lane == 0) {
        float* o = out + (size_t)(pair * SAMPLES + 1) * (4 * NCOL) + q * NCOL;
#pragma unroll
        for (int c = 0; c < NCOL; ++c)
            atomicAdd(o + c, acc[c]);
    }
#undef COMPUTE
}

extern "C" void kernel_launch(void* const* d_in, const int* in_sizes, int n_in,
                              void* d_out, int out_size, void* d_ws, size_t ws_size,
                              hipStream_t stream) {
    const float* x = (const float*)d_in[0];
    const float* u = (const float*)d_in[1];
    const float* v = (const float*)d_in[2];
    float* out = (float*)d_out;

    const int b_count = in_sizes[0] / (NALL * NALL);   // 128

    // zero the accumulated output every call (atomics accumulate into it)
    (void)hipMemsetAsync(d_out, 0, (size_t)out_size * sizeof(float), stream);

    dim3 grid((b_count / SAMPLES) * CHUNKS);   // 1024
    jxy_kernel<<<grid, THREADS, 0, stream>>>(x, u, v, out);
}

// Round 9
// 113.578 us; speedup vs baseline: 1.4580x; 1.4580x over previous
//
#include <hip/hip_runtime.h>

#define NALL 1024
#define NH   512
#define NCOL 8
#define ROWS_PER_BLOCK 64
#define THREADS 256
#define CHUNKS (NALL / ROWS_PER_BLOCK)   // 16
#define SAMPLES 2                        // samples per block (amortize prologue)

typedef float f32x4 __attribute__((ext_vector_type(4)));

// R6 structure (best measured: 96.1 us), single change: plain loads instead
// of nontemporal (A/B of the nt flag; everything else identical).
// Block = (sample pair, 64-row chunk). Prologue (joint column norms of
// concat(u,v), normalized left rows in LDS, right fragment in regs) is
// sample-independent -> computed once; then the block streams 2 samples'
// worth of x rows (512 KB contiguous per sample-chunk). grid = 1024 = one
// resident generation at 4 blocks/CU.
// out[b][q*8+c], q = ih + 2*jh:
//   q0 = uJu (i<512, j<512),  q1 = vJu (i>=512, j<512),
//   q2 = uJv (i<512, j>=512), q3 = vJv (i>=512, j>=512)
__global__ __launch_bounds__(THREADS) void jxy_kernel(
    const float* __restrict__ x, const float* __restrict__ u,
    const float* __restrict__ v, float* __restrict__ out) {
    const int bid   = blockIdx.x;
    const int pair  = bid >> 4;          // sample pair index
    const int chunk = bid & (CHUNKS - 1);
    const int r0    = chunk * ROWS_PER_BLOCK;
    const int ih    = (r0 >= NH) ? 1 : 0;   // 64-row chunks never straddle halves
    const int rloc  = r0 - ih * NH;

    const int tid  = threadIdx.x;
    const int wave = tid >> 6;
    const int lane = tid & 63;
    const int jbase = wave * 256 + lane * 4;   // this lane's 4 fixed j positions
    const int jh    = (jbase >= NH) ? 1 : 0;   // uniform per wave
    const int jloc  = jbase - jh * NH;

    // ---- phase 1: joint column norms of concat(u,v) ----
    __shared__ float red[THREADS];
    __shared__ float inv_norm[NCOL];
    {
        const int c   = tid & 7;
        const int seg = tid >> 3;    // 0..31
        float s = 0.f;
        for (int r = seg; r < NH; r += 32) {
            float a = u[r * NCOL + c];
            float bb = v[r * NCOL + c];
            s = fmaf(a, a, fmaf(bb, bb, s));
        }
        red[tid] = s;
        __syncthreads();
        for (int off = THREADS / 2; off >= NCOL; off >>= 1) {
            if (tid < off) red[tid] += red[tid + off];
            __syncthreads();
        }
        if (tid < NCOL) inv_norm[tid] = 1.0f / sqrtf(red[tid]);
        __syncthreads();
    }

    // ---- phase 2: stage normalized left rows (LDS) + right fragment (regs) ----
    __shared__ __align__(16) float wl[ROWS_PER_BLOCK * NCOL];
    const float* rawl = ih ? v : u;
    for (int idx = tid; idx < ROWS_PER_BLOCK * NCOL; idx += THREADS)
        wl[idx] = rawl[rloc * NCOL + idx] * inv_norm[idx & 7];

    const float* rawr = jh ? v : u;
    float wr[4][NCOL];
#pragma unroll
    for (int k = 0; k < 4; ++k) {
        const float4* p = reinterpret_cast<const float4*>(rawr + (size_t)(jloc + k) * NCOL);
        float4 a = p[0];
        float4 bq = p[1];
        wr[k][0] = a.x * inv_norm[0];  wr[k][1] = a.y * inv_norm[1];
        wr[k][2] = a.z * inv_norm[2];  wr[k][3] = a.w * inv_norm[3];
        wr[k][4] = bq.x * inv_norm[4]; wr[k][5] = bq.y * inv_norm[5];
        wr[k][6] = bq.z * inv_norm[6]; wr[k][7] = bq.w * inv_norm[7];
    }
    __syncthreads();

    // ---- phase 3+4 per sample: stream 64 rows, reduce, one atomic set ----
    for (int s = 0; s < SAMPLES; ++s) {
        const int b = pair * SAMPLES + s;

        float acc[NCOL];
#pragma unroll
        for (int c = 0; c < NCOL; ++c) acc[c] = 0.f;

        const float* xrow = x + ((size_t)b * NALL + r0) * NALL + jbase;

#pragma unroll 8
        for (int r = 0; r < ROWS_PER_BLOCK; ++r) {
            f32x4 xv = *reinterpret_cast<const f32x4*>(xrow + (size_t)r * NALL);

            float t[NCOL];
#pragma unroll
            for (int c = 0; c < NCOL; ++c)
                t[c] = fmaf(xv.x, wr[0][c],
                       fmaf(xv.y, wr[1][c],
                       fmaf(xv.z, wr[2][c],
                            xv.w * wr[3][c])));

            // wave-uniform broadcast reads from LDS (no bank conflict)
            float4 wa = *reinterpret_cast<const float4*>(&wl[r * NCOL]);
            float4 wb = *reinterpret_cast<const float4*>(&wl[r * NCOL + 4]);
            acc[0] = fmaf(wa.x, t[0], acc[0]);
            acc[1] = fmaf(wa.y, t[1], acc[1]);
            acc[2] = fmaf(wa.z, t[2], acc[2]);
            acc[3] = fmaf(wa.w, t[3], acc[3]);
            acc[4] = fmaf(wb.x, t[4], acc[4]);
            acc[5] = fmaf(wb.y, t[5], acc[5]);
            acc[6] = fmaf(wb.z, t[6], acc[6]);
            acc[7] = fmaf(wb.w, t[7], acc[7]);
        }

        // wave butterfly reduce (8 values x 6 steps)
#pragma unroll
        for (int c = 0; c < NCOL; ++c) {
#pragma unroll
            for (int off = 32; off >= 1; off >>= 1)
                acc[c] += __shfl_xor(acc[c], off, 64);
        }

        if (lane == 0) {
            const int q = ih + 2 * jh;
            float* o = out + (size_t)b * (4 * NCOL) + q * NCOL;
#pragma unroll
            for (int c = 0; c < NCOL; ++c)
                atomicAdd(o + c, acc[c]);
        }
    }
}

extern "C" void kernel_launch(void* const* d_in, const int* in_sizes, int n_in,
                              void* d_out, int out_size, void* d_ws, size_t ws_size,
                              hipStream_t stream) {
    const float* x = (const float*)d_in[0];
    const float* u = (const float*)d_in[1];
    const float* v = (const float*)d_in[2];
    float* out = (float*)d_out;

    const int b_count = in_sizes[0] / (NALL * NALL);   // 128

    // zero the accumulated output every call (atomics accumulate into it)
    (void)hipMemsetAsync(d_out, 0, (size_t)out_size * sizeof(float), stream);

    dim3 grid((b_count / SAMPLES) * CHUNKS);   // 1024
    jxy_kernel<<<grid, THREADS, 0, stream>>>(x, u, v, out);
}

// Round 10
// 95.166 us; speedup vs baseline: 1.7401x; 1.1935x over previous
//
#include <hip/hip_runtime.h>

#define NALL 1024
#define NH   512
#define NCOL 8
#define ROWS_PER_BLOCK 64
#define THREADS 256
#define CHUNKS (NALL / ROWS_PER_BLOCK)   // 16
#define SAMPLES 2                        // samples per block (amortize prologue)

typedef float f32x4 __attribute__((ext_vector_type(4)));

// Best-measured structure (R6, 96.1 us), restored verbatim after the R9 A/B
// proved nontemporal loads are a ~15% win for this read-once 512 MB stream.
// Block = (sample pair, 64-row chunk). Prologue (joint column norms of
// concat(u,v), normalized left rows in LDS, right fragment in regs) is
// sample-independent -> computed once; then the block streams 2 samples'
// worth of x rows. grid = 1024 = one resident generation at 4 blocks/CU.
// out[b][q*8+c], q = ih + 2*jh:
//   q0 = uJu (i<512, j<512),  q1 = vJu (i>=512, j<512),
//   q2 = uJv (i<512, j>=512), q3 = vJv (i>=512, j>=512)
__global__ __launch_bounds__(THREADS) void jxy_kernel(
    const float* __restrict__ x, const float* __restrict__ u,
    const float* __restrict__ v, float* __restrict__ out) {
    const int bid   = blockIdx.x;
    const int pair  = bid >> 4;          // sample pair index
    const int chunk = bid & (CHUNKS - 1);
    const int r0    = chunk * ROWS_PER_BLOCK;
    const int ih    = (r0 >= NH) ? 1 : 0;   // 64-row chunks never straddle halves
    const int rloc  = r0 - ih * NH;

    const int tid  = threadIdx.x;
    const int wave = tid >> 6;
    const int lane = tid & 63;
    const int jbase = wave * 256 + lane * 4;   // this lane's 4 fixed j positions
    const int jh    = (jbase >= NH) ? 1 : 0;   // uniform per wave
    const int jloc  = jbase - jh * NH;

    // ---- phase 1: joint column norms of concat(u,v) ----
    __shared__ float red[THREADS];
    __shared__ float inv_norm[NCOL];
    {
        const int c   = tid & 7;
        const int seg = tid >> 3;    // 0..31
        float s = 0.f;
        for (int r = seg; r < NH; r += 32) {
            float a = u[r * NCOL + c];
            float bb = v[r * NCOL + c];
            s = fmaf(a, a, fmaf(bb, bb, s));
        }
        red[tid] = s;
        __syncthreads();
        for (int off = THREADS / 2; off >= NCOL; off >>= 1) {
            if (tid < off) red[tid] += red[tid + off];
            __syncthreads();
        }
        if (tid < NCOL) inv_norm[tid] = 1.0f / sqrtf(red[tid]);
        __syncthreads();
    }

    // ---- phase 2: stage normalized left rows (LDS) + right fragment (regs) ----
    __shared__ __align__(16) float wl[ROWS_PER_BLOCK * NCOL];
    const float* rawl = ih ? v : u;
    for (int idx = tid; idx < ROWS_PER_BLOCK * NCOL; idx += THREADS)
        wl[idx] = rawl[rloc * NCOL + idx] * inv_norm[idx & 7];

    const float* rawr = jh ? v : u;
    float wr[4][NCOL];
#pragma unroll
    for (int k = 0; k < 4; ++k) {
        const float4* p = reinterpret_cast<const float4*>(rawr + (size_t)(jloc + k) * NCOL);
        float4 a = p[0];
        float4 bq = p[1];
        wr[k][0] = a.x * inv_norm[0];  wr[k][1] = a.y * inv_norm[1];
        wr[k][2] = a.z * inv_norm[2];  wr[k][3] = a.w * inv_norm[3];
        wr[k][4] = bq.x * inv_norm[4]; wr[k][5] = bq.y * inv_norm[5];
        wr[k][6] = bq.z * inv_norm[6]; wr[k][7] = bq.w * inv_norm[7];
    }
    __syncthreads();

    // ---- phase 3+4 per sample: stream 64 rows, reduce, one atomic set ----
    for (int s = 0; s < SAMPLES; ++s) {
        const int b = pair * SAMPLES + s;

        float acc[NCOL];
#pragma unroll
        for (int c = 0; c < NCOL; ++c) acc[c] = 0.f;

        const float* xrow = x + ((size_t)b * NALL + r0) * NALL + jbase;

#pragma unroll 8
        for (int r = 0; r < ROWS_PER_BLOCK; ++r) {
            f32x4 xv = __builtin_nontemporal_load(
                reinterpret_cast<const f32x4*>(xrow + (size_t)r * NALL));

            float t[NCOL];
#pragma unroll
            for (int c = 0; c < NCOL; ++c)
                t[c] = fmaf(xv.x, wr[0][c],
                       fmaf(xv.y, wr[1][c],
                       fmaf(xv.z, wr[2][c],
                            xv.w * wr[3][c])));

            // wave-uniform broadcast reads from LDS (no bank conflict)
            float4 wa = *reinterpret_cast<const float4*>(&wl[r * NCOL]);
            float4 wb = *reinterpret_cast<const float4*>(&wl[r * NCOL + 4]);
            acc[0] = fmaf(wa.x, t[0], acc[0]);
            acc[1] = fmaf(wa.y, t[1], acc[1]);
            acc[2] = fmaf(wa.z, t[2], acc[2]);
            acc[3] = fmaf(wa.w, t[3], acc[3]);
            acc[4] = fmaf(wb.x, t[4], acc[4]);
            acc[5] = fmaf(wb.y, t[5], acc[5]);
            acc[6] = fmaf(wb.z, t[6], acc[6]);
            acc[7] = fmaf(wb.w, t[7], acc[7]);
        }

        // wave butterfly reduce (8 values x 6 steps)
#pragma unroll
        for (int c = 0; c < NCOL; ++c) {
#pragma unroll
            for (int off = 32; off >= 1; off >>= 1)
                acc[c] += __shfl_xor(acc[c], off, 64);
        }

        if (lane == 0) {
            const int q = ih + 2 * jh;
            float* o = out + (size_t)b * (4 * NCOL) + q * NCOL;
#pragma unroll
            for (int c = 0; c < NCOL; ++c)
                atomicAdd(o + c, acc[c]);
        }
    }
}

extern "C" void kernel_launch(void* const* d_in, const int* in_sizes, int n_in,
                              void* d_out, int out_size, void* d_ws, size_t ws_size,
                              hipStream_t stream) {
    const float* x = (const float*)d_in[0];
    const float* u = (const float*)d_in[1];
    const float* v = (const float*)d_in[2];
    float* out = (float*)d_out;

    const int b_count = in_sizes[0] / (NALL * NALL);   // 128

    // zero the accumulated output every call (atomics accumulate into it)
    (void)hipMemsetAsync(d_out, 0, (size_t)out_size * sizeof(float), stream);

    dim3 grid((b_count / SAMPLES) * CHUNKS);   // 1024
    jxy_kernel<<<grid, THREADS, 0, stream>>>(x, u, v, out);
}